// Round 6
// baseline (212.337 us; speedup 1.0000x reference)
//
#include <hip/hip_runtime.h>

typedef short bf16x8 __attribute__((ext_vector_type(8)));
typedef float f32x4 __attribute__((ext_vector_type(4)));
typedef unsigned int u32;
typedef __attribute__((address_space(1))) const u32 gu32;
typedef __attribute__((address_space(3))) u32 lu32;

#define NEG_INF (-__builtin_inff())

static __device__ __forceinline__ unsigned short f2bf(float f) {
  union { float f; unsigned u; } v; v.f = f;
  return (unsigned short)((v.u + 0x7fffu + ((v.u >> 16) & 1u)) >> 16);
}
static __device__ __forceinline__ unsigned fbits(float f) {
  union { float f; unsigned u; } v; v.f = f;
  return v.u;
}
// pack two floats to packed bf16 (round-half-up): low16 = a, high16 = b
static __device__ __forceinline__ unsigned pack2(float a, float b) {
  return __builtin_amdgcn_perm(fbits(b) + 0x8000u, fbits(a) + 0x8000u, 0x07060302u);
}
static __device__ __forceinline__ f32x4 mfma16(bf16x8 a, bf16x8 b, f32x4 c) {
  return __builtin_amdgcn_mfma_f32_16x16x32_bf16(a, b, c, 0, 0, 0);
}
// async DMA: 64 lanes x 16B -> contiguous 1KB LDS at (uniform) l + lane*16
static __device__ __forceinline__ void dma16(const void* g, void* l) {
  __builtin_amdgcn_global_load_lds((gu32*)g, (lu32*)l, 16, 0, 0);
}

// ---- attn helpers (register double-buffer pipeline, as R5) ----
static __device__ __forceinline__ void load_tile(const char* kg, const char* vg,
                                                 int lo, int quad, int swz,
                                                 bf16x8 (&kf)[8], bf16x8 (&vf)[8]) {
#pragma unroll
  for (int t = 0; t < 4; ++t) {
    const int row = (t * 16 + lo) * 128;
    kf[2 * t] = *(const bf16x8*)(kg + row + ((quad ^ swz) << 4));
    kf[2 * t + 1] = *(const bf16x8*)(kg + row + (((4 + quad) ^ swz) << 4));
  }
#pragma unroll
  for (int kk2 = 0; kk2 < 2; ++kk2) {
#pragma unroll
    for (int dt = 0; dt < 4; ++dt) {
      const int rowv = (dt * 16 + lo) * 128;
      vf[kk2 * 4 + dt] = *(const bf16x8*)(vg + rowv + (((kk2 * 4 + quad) ^ swz) << 4));
    }
  }
}

static __device__ __forceinline__ void compute_tile(
    const bf16x8 (&kf)[8], const bf16x8 (&vf)[8], bf16x8 bq0, bf16x8 bq1,
    unsigned short* psw /* wave-private, row stride 72 */, int lo, int quad,
    bool diag, int key0, int qrl, f32x4 (&oacc)[4], float& l) {
#pragma unroll
  for (int t = 0; t < 4; ++t) {
    f32x4 s = (f32x4){0.f, 0.f, 0.f, 0.f};
    s = mfma16(kf[2 * t], bq0, s);
    s = mfma16(kf[2 * t + 1], bq1, s);
    if (diag) {
#pragma unroll
      for (int r = 0; r < 4; ++r)
        if (key0 + t * 16 + quad * 4 + r > qrl) s[r] = NEG_INF;
    }
    float e0 = __builtin_amdgcn_exp2f(s[0]);
    float e1 = __builtin_amdgcn_exp2f(s[1]);
    float e2 = __builtin_amdgcn_exp2f(s[2]);
    float e3 = __builtin_amdgcn_exp2f(s[3]);
    l += (e0 + e1) + (e2 + e3);
    uint2 uu;
    uu.x = pack2(e0, e1);
    uu.y = pack2(e2, e3);
    *(uint2*)(psw + lo * 72 + t * 16 + quad * 4) = uu;
  }
  asm volatile("s_waitcnt lgkmcnt(0)" ::: "memory");  // wave-private ps
#pragma unroll
  for (int kk2 = 0; kk2 < 2; ++kk2) {
    bf16x8 bp = *(const bf16x8*)(psw + lo * 72 + kk2 * 32 + quad * 8);
#pragma unroll
    for (int dt = 0; dt < 4; ++dt) {
      oacc[dt] = mfma16(vf[kk2 * 4 + dt], bp, oacc[dt]);
    }
  }
}

// ================== PATH A: fused kernel, flag-based ordering ==================
// Cooperative launch is used ONLY for the co-residency guarantee (512 blocks =
// exactly 2/CU); NO grid.sync / per-wave fences (R3's 300us lesson). Ordering:
// producers __syncthreads (drains vmcnt -> stores at L2), then tid0 does ONE
// __threadfence (L2 writeback to L3) + atomicAdd; consumers spin (acquire,
// s_sleep) then __syncthreads. Consumers' caches hold no stale copies of the
// flagged data (first touch after the release), so no invalidate is needed.
// Block (b,g) does proj for its own 64 tokens AND attn for q-group a=g of the
// same batch -> Q stays in-block (2KB wave-private LDS bounce, qo deleted).
// Index map (R5 attn map, now shared by both phases) keeps co-resident pairs
// at g1+g2=31 -> balanced attn makespan.
__global__ __launch_bounds__(256, 2) void fused_kernel(
    const float* __restrict__ x, const float* __restrict__ wq,
    const float* __restrict__ wk, const float* __restrict__ wv,
    char* __restrict__ wt, char* __restrict__ kT, char* __restrict__ vT,
    u32* __restrict__ flags, float* __restrict__ out) {
  __shared__ __align__(16) union {
    char wls[2][24576];                 // proj: W staging (48 KB)
    unsigned short ps[4][16][72];       // attn: Q bounce + wave-private P^T
  } sm;

  const int tid = threadIdx.x;
  const int bid = blockIdx.x;
  const int wave = tid >> 6, lane = tid & 63;
  const int lo = lane & 15, quad = lane >> 4;

  const int b = bid & 15;
  const int idx = bid >> 4;
  const int g = (bid < 256) ? (31 - idx) : (idx - 16);
  const long tok0 = (long)b * 2048 + g * 64 + wave * 16;

  // ---- phase 0: W scatter (blocks 0..95 cover 96*256 = 24576 elements)
  if (bid < 96) {
    const int i = bid * 256 + tid;
    const int c = i >> 6, d = i & 63;
    const int c6 = c >> 6, cin = c & 63;
    const float Cs = 0.18033688011112042f;  // 0.125 * log2(e): Q pre-scale
    const long base = (long)(c6 * 192) * 128;
    const int col = (cin * 2) ^ ((d & 7) << 4);
    *(unsigned short*)(wt + base + (long)d * 128 + col) = f2bf(wq[i] * Cs);
    *(unsigned short*)(wt + base + (long)(64 + d) * 128 + col) = f2bf(wk[i]);
    *(unsigned short*)(wt + base + (long)(128 + d) * 128 + col) = f2bf(wv[i]);
  }

  // ---- phase 0b: x -> registers (HBM latency hides under scatter + spin)
  bf16x8 ax[12];
  {
    const float* xr = x + (tok0 + lo) * 384 + quad * 8;
#pragma unroll
    for (int kk = 0; kk < 12; ++kk) {
      float4 x0 = *(const float4*)(xr + kk * 32);
      float4 x1 = *(const float4*)(xr + kk * 32 + 4);
      bf16x8 a2;
      a2[0] = (short)f2bf(x0.x); a2[1] = (short)f2bf(x0.y);
      a2[2] = (short)f2bf(x0.z); a2[3] = (short)f2bf(x0.w);
      a2[4] = (short)f2bf(x1.x); a2[5] = (short)f2bf(x1.y);
      a2[6] = (short)f2bf(x1.z); a2[7] = (short)f2bf(x1.w);
      ax[kk] = a2;
    }
  }

  // ---- flag barrier 1: wt ready (96 producers)
  __syncthreads();  // drains vmcnt: this block's wt stores are at L2
  if (tid == 0) {
    if (bid < 96) {
      __threadfence();               // push this XCD's dirty L2 (wt) to L3
      atomicAdd(&flags[0], 1u);      // device-scope
    }
    while (__hip_atomic_load(&flags[0], __ATOMIC_ACQUIRE,
                             __HIP_MEMORY_SCOPE_AGENT) < 96u)
      __builtin_amdgcn_s_sleep(8);
  }
  __syncthreads();

  // ---- phase 1: QKV projection (R5 proj, Q kept in registers) ----
  uint2 qu[4];
  {
#pragma unroll
    for (int s2 = 0; s2 < 6; ++s2) {
      const int s = wave * 6 + s2;
      dma16(wt + s * 1024 + lane * 16, &sm.wls[0][s * 1024]);
    }
    f32x4 acc[12];
#pragma unroll
    for (int nt = 0; nt < 12; ++nt) acc[nt] = (f32x4){0.f, 0.f, 0.f, 0.f};

    for (int c6 = 0; c6 < 6; ++c6) {
      const int buf = c6 & 1;
      __syncthreads();                       // chunk c6 resident; buf^1 free
      if (c6 < 5) {
        const char* wg = wt + (long)(c6 + 1) * 24576;
#pragma unroll
        for (int s2 = 0; s2 < 6; ++s2) {
          const int s = wave * 6 + s2;
          dma16(wg + s * 1024 + lane * 16, &sm.wls[buf ^ 1][s * 1024]);
        }
      }
#pragma unroll
      for (int kk = 0; kk < 2; ++kk) {
        const bf16x8 axk = ax[c6 * 2 + kk];
#pragma unroll
        for (int nt = 0; nt < 12; ++nt) {
          const int dd = nt * 16 + lo;
          const int col = ((kk * 4 + quad) ^ (lo & 7)) << 4;
          bf16x8 wf = *(const bf16x8*)(&sm.wls[buf][dd * 128 + col]);
          if (nt < 8)
            acc[nt] = mfma16(wf, axk, acc[nt]);   // Q,K: C[d][token]
          else
            acc[nt] = mfma16(axk, wf, acc[nt]);   // V:   C[token][d]
        }
      }
    }

    // epilogue: K/V to global; Q fragments stay in qu[]
    const long tile = ((long)(b * 32 + g) << 13);   // 8192 B per tile
    const int tin = wave * 16;                      // token-in-tile base
    const int key0w = tin + quad * 4;
    const int keyl = tin + lo;
#pragma unroll
    for (int nt = 0; nt < 12; ++nt) {
      uint2 uu;
      uu.x = pack2(acc[nt][0], acc[nt][1]);
      uu.y = pack2(acc[nt][2], acc[nt][3]);
      if (nt < 4) {
        qu[nt] = uu;
      } else if (nt < 8) {
        const int d0 = (nt - 4) * 16 + quad * 4;
        *(uint2*)(kT + tile + keyl * 128 + (((d0 * 2) ^ ((keyl & 7) << 4)))) = uu;
      } else {
        const int d = (nt - 8) * 16 + lo;
        *(uint2*)(vT + tile + d * 128 + (((key0w * 2) ^ ((d & 7) << 4)))) = uu;
      }
    }
  }

  // ---- flag barrier 2: K/V tiles of my batch ready (32 producers per batch)
  __syncthreads();  // drains vmcnt: kT/vT stores at L2
  if (tid == 0) {
    __threadfence();                        // push to L3 for other XCDs
    atomicAdd(&flags[16 + 16 * b], 1u);
    while (__hip_atomic_load(&flags[16 + 16 * b], __ATOMIC_ACQUIRE,
                             __HIP_MEMORY_SCOPE_AGENT) < 32u)
      __builtin_amdgcn_s_sleep(8);
  }
  __syncthreads();

  // ---- phase 2: causal flash attention (a = g), Q from registers ----
  {
    const int niter = g + 1;
    const int qrow0 = (4 * g + wave) * 16;
    const char* kbT = kT + ((long)b * 32 << 13);
    const char* vbT = vT + ((long)b * 32 << 13);
    float* ob = out + (long)b * 2048 * 64;
    unsigned short* psw = &sm.ps[wave][0][0];

    // Q bounce: reg (proj layout) -> wave-private LDS -> attn B-operand layout
#pragma unroll
    for (int nt = 0; nt < 4; ++nt)
      *(uint2*)(psw + lo * 72 + nt * 16 + quad * 4) = qu[nt];
    asm volatile("s_waitcnt lgkmcnt(0)" ::: "memory");
    const bf16x8 bq0 = *(const bf16x8*)(psw + lo * 72 + quad * 8);
    const bf16x8 bq1 = *(const bf16x8*)(psw + lo * 72 + 32 + quad * 8);

    f32x4 oacc[4];
#pragma unroll
    for (int dt = 0; dt < 4; ++dt) oacc[dt] = (f32x4){0.f, 0.f, 0.f, 0.f};
    float l = 0.f;
    const int swz = (lo & 7);
    const int qrl = qrow0 + lo;

    bf16x8 kA[8], vA[8], kB[8], vB[8];
    load_tile(kbT, vbT, lo, quad, swz, kA, vA);

    int kt = 0;
    for (; kt + 2 <= niter; kt += 2) {
      load_tile(kbT + ((long)(kt + 1) << 13), vbT + ((long)(kt + 1) << 13), lo,
                quad, swz, kB, vB);
      compute_tile(kA, vA, bq0, bq1, psw, lo, quad, /*diag=*/false, kt * 64,
                   qrl, oacc, l);
      if (kt + 2 < niter)
        load_tile(kbT + ((long)(kt + 2) << 13), vbT + ((long)(kt + 2) << 13),
                  lo, quad, swz, kA, vA);
      compute_tile(kB, vB, bq0, bq1, psw, lo, quad,
                   /*diag=*/(kt + 1 == niter - 1), (kt + 1) * 64, qrl, oacc, l);
    }
    if (kt < niter) {
      compute_tile(kA, vA, bq0, bq1, psw, lo, quad, /*diag=*/true, kt * 64,
                   qrl, oacc, l);
    }

    l += __shfl_xor(l, 16, 64);
    l += __shfl_xor(l, 32, 64);
    const float inv = 1.0f / l;
    float* orow = ob + (long)(qrow0 + lo) * 64;
#pragma unroll
    for (int dt = 0; dt < 4; ++dt) {
      float4 stv;
      stv.x = oacc[dt][0] * inv; stv.y = oacc[dt][1] * inv;
      stv.z = oacc[dt][2] * inv; stv.w = oacc[dt][3] * inv;
      *(float4*)(orow + dt * 16 + quad * 4) = stv;
    }
  }
}

// ================== PATH B: known-good 3-kernel fallback (R5) ==================
__global__ __launch_bounds__(256) void prep_w(const float* __restrict__ wq,
                                              const float* __restrict__ wk,
                                              const float* __restrict__ wv,
                                              char* __restrict__ wt) {
  int i = blockIdx.x * 256 + threadIdx.x;
  if (i >= 384 * 64) return;
  int c = i >> 6, d = i & 63;
  int c6 = c >> 6, cin = c & 63;
  const float Cs = 0.18033688011112042f;
  long base = (long)(c6 * 192) * 128;
  int col = (cin * 2) ^ ((d & 7) << 4);
  *(unsigned short*)(wt + base + (long)d * 128 + col) = f2bf(wq[i] * Cs);
  *(unsigned short*)(wt + base + (long)(64 + d) * 128 + col) = f2bf(wk[i]);
  *(unsigned short*)(wt + base + (long)(128 + d) * 128 + col) = f2bf(wv[i]);
}

__global__ __launch_bounds__(256, 2) void proj_kernel(
    const float* __restrict__ x, const char* __restrict__ wt,
    unsigned short* __restrict__ qo, char* __restrict__ kT,
    char* __restrict__ vT) {
  __shared__ char wls[2][24576];
  const int tid = threadIdx.x;
  const int wave = tid >> 6, lane = tid & 63;
  const int lo = lane & 15, quad = lane >> 4;
  const long tok0 = ((long)blockIdx.x * 4 + wave) * 16;

#pragma unroll
  for (int s2 = 0; s2 < 6; ++s2) {
    const int s = wave * 6 + s2;
    dma16(wt + s * 1024 + lane * 16, &wls[0][s * 1024]);
  }
  bf16x8 ax[12];
  const float* xr = x + (tok0 + lo) * 384 + quad * 8;
#pragma unroll
  for (int kk = 0; kk < 12; ++kk) {
    float4 x0 = *(const float4*)(xr + kk * 32);
    float4 x1 = *(const float4*)(xr + kk * 32 + 4);
    bf16x8 a;
    a[0] = (short)f2bf(x0.x); a[1] = (short)f2bf(x0.y);
    a[2] = (short)f2bf(x0.z); a[3] = (short)f2bf(x0.w);
    a[4] = (short)f2bf(x1.x); a[5] = (short)f2bf(x1.y);
    a[6] = (short)f2bf(x1.z); a[7] = (short)f2bf(x1.w);
    ax[kk] = a;
  }

  f32x4 acc[12];
#pragma unroll
  for (int nt = 0; nt < 12; ++nt) acc[nt] = (f32x4){0.f, 0.f, 0.f, 0.f};

  for (int c6 = 0; c6 < 6; ++c6) {
    const int buf = c6 & 1;
    __syncthreads();
    if (c6 < 5) {
      const char* wg = wt + (long)(c6 + 1) * 24576;
#pragma unroll
      for (int s2 = 0; s2 < 6; ++s2) {
        const int s = wave * 6 + s2;
        dma16(wg + s * 1024 + lane * 16, &wls[buf ^ 1][s * 1024]);
      }
    }
#pragma unroll
    for (int kk = 0; kk < 2; ++kk) {
      const bf16x8 axk = ax[c6 * 2 + kk];
#pragma unroll
      for (int nt = 0; nt < 12; ++nt) {
        const int dd = nt * 16 + lo;
        const int col = ((kk * 4 + quad) ^ (lo & 7)) << 4;
        bf16x8 wf = *(const bf16x8*)(&wls[buf][dd * 128 + col]);
        if (nt < 8)
          acc[nt] = mfma16(wf, axk, acc[nt]);
        else
          acc[nt] = mfma16(axk, wf, acc[nt]);
      }
    }
  }

  const long bb = tok0 >> 11;
  const int tin0 = (int)(tok0 & 2047);
  const int kt = tin0 >> 6;
  const long tile = ((bb * 32 + kt) << 13);
  const int key0w = (tin0 & 63) + quad * 4;
  const int keyl = (tin0 & 63) + lo;
#pragma unroll
  for (int nt = 0; nt < 12; ++nt) {
    uint2 uu;
    uu.x = pack2(acc[nt][0], acc[nt][1]);
    uu.y = pack2(acc[nt][2], acc[nt][3]);
    if (nt < 4) {
      *(uint2*)(qo + (tok0 + lo) * 64 + nt * 16 + quad * 4) = uu;
    } else if (nt < 8) {
      const int d0 = (nt - 4) * 16 + quad * 4;
      *(uint2*)(kT + tile + keyl * 128 + (((d0 * 2) ^ ((keyl & 7) << 4)))) = uu;
    } else {
      const int d = (nt - 8) * 16 + lo;
      *(uint2*)(vT + tile + d * 128 + (((key0w * 2) ^ ((d & 7) << 4)))) = uu;
    }
  }
}

__global__ __launch_bounds__(256, 2) void attn_kernel(
    const unsigned short* __restrict__ qg, const char* __restrict__ kT,
    const char* __restrict__ vT, float* __restrict__ out) {
  __shared__ unsigned short ps[4][16][72];

  const int tid = threadIdx.x;
  const int h = tid >> 6, lane = tid & 63;
  const int lo = lane & 15, quad = lane >> 4;
  const int b = blockIdx.x & 15;
  const int idx = blockIdx.x >> 4;
  const int a = (blockIdx.x < 256) ? (31 - idx) : (idx - 16);
  const int j = 4 * a + h;
  const int niter = a + 1;
  const int qrow0 = j * 16;

  const unsigned short* qb = qg + (long)b * 2048 * 64;
  const char* kbT = kT + ((long)b * 32 << 13);
  const char* vbT = vT + ((long)b * 32 << 13);
  float* ob = out + (long)b * 2048 * 64;

  const unsigned short* qr = qb + (long)(qrow0 + lo) * 64 + quad * 8;
  const bf16x8 bq0 = *(const bf16x8*)qr;
  const bf16x8 bq1 = *(const bf16x8*)(qr + 32);

  f32x4 oacc[4];
#pragma unroll
  for (int dt = 0; dt < 4; ++dt) oacc[dt] = (f32x4){0.f, 0.f, 0.f, 0.f};
  float l = 0.f;
  const int swz = (lo & 7);
  const int qrl = qrow0 + lo;
  unsigned short* psw = &ps[h][0][0];

  bf16x8 kA[8], vA[8], kB[8], vB[8];
  load_tile(kbT, vbT, lo, quad, swz, kA, vA);

  int kt = 0;
  for (; kt + 2 <= niter; kt += 2) {
    load_tile(kbT + ((long)(kt + 1) << 13), vbT + ((long)(kt + 1) << 13), lo,
              quad, swz, kB, vB);
    compute_tile(kA, vA, bq0, bq1, psw, lo, quad, /*diag=*/false, kt * 64, qrl,
                 oacc, l);
    if (kt + 2 < niter)
      load_tile(kbT + ((long)(kt + 2) << 13), vbT + ((long)(kt + 2) << 13), lo,
                quad, swz, kA, vA);
    compute_tile(kB, vB, bq0, bq1, psw, lo, quad,
                 /*diag=*/(kt + 1 == niter - 1), (kt + 1) * 64, qrl, oacc, l);
  }
  if (kt < niter) {
    compute_tile(kA, vA, bq0, bq1, psw, lo, quad, /*diag=*/true, kt * 64, qrl,
                 oacc, l);
  }

  l += __shfl_xor(l, 16, 64);
  l += __shfl_xor(l, 32, 64);
  const float inv = 1.0f / l;
  float* orow = ob + (long)(qrow0 + lo) * 64;
#pragma unroll
  for (int dt = 0; dt < 4; ++dt) {
    float4 st;
    st.x = oacc[dt][0] * inv; st.y = oacc[dt][1] * inv;
    st.z = oacc[dt][2] * inv; st.w = oacc[dt][3] * inv;
    *(float4*)(orow + dt * 16 + quad * 4) = st;
  }
}

// ---------------- launcher ----------------
extern "C" void kernel_launch(void* const* d_in, const int* in_sizes, int n_in,
                              void* d_out, int out_size, void* d_ws, size_t ws_size,
                              hipStream_t stream) {
  const float* x = (const float*)d_in[0];
  const float* wq = (const float*)d_in[1];
  const float* wk = (const float*)d_in[2];
  const float* wv = (const float*)d_in[3];
  float* out = (float*)d_out;

  char* ws = (char*)d_ws;
  char* wt = ws;                                   // 147456 B
  u32* flags = (u32*)(ws + 151552);                // 2 KB flag region
  char* kT = ws + (4 << 20);
  char* vT = ws + (8 << 20);

  hipMemsetAsync(flags, 0, 2048, stream);          // re-zero each graph iter

  void* args[] = {(void*)&x,  (void*)&wq, (void*)&wk,    (void*)&wv, (void*)&wt,
                  (void*)&kT, (void*)&vT, (void*)&flags, (void*)&out};
  hipError_t e = hipLaunchCooperativeKernel(
      reinterpret_cast<const void*>(&fused_kernel), dim3(512), dim3(256), args,
      0u, stream);
  if (e != hipSuccess) {
    // known-good 3-kernel path (125.4 us baseline)
    unsigned short* qws = (unsigned short*)(ws + (12 << 20));
    prep_w<<<96, 256, 0, stream>>>(wq, wk, wv, wt);
    proj_kernel<<<512, 256, 0, stream>>>(x, wt, qws, kT, vT);
    attn_kernel<<<512, 256, 0, stream>>>(qws, kT, vT, out);
  }
}

// Round 7
// 138.834 us; speedup vs baseline: 1.5294x; 1.5294x over previous
//
#include <hip/hip_runtime.h>

typedef short bf16x8 __attribute__((ext_vector_type(8)));
typedef float f32x4 __attribute__((ext_vector_type(4)));
typedef unsigned int u32;
typedef __attribute__((address_space(1))) const u32 gu32;
typedef __attribute__((address_space(3))) u32 lu32;

#define NEG_INF (-__builtin_inff())

static __device__ __forceinline__ unsigned short f2bf(float f) {
  union { float f; unsigned u; } v; v.f = f;
  return (unsigned short)((v.u + 0x7fffu + ((v.u >> 16) & 1u)) >> 16);
}
static __device__ __forceinline__ unsigned fbits(float f) {
  union { float f; unsigned u; } v; v.f = f;
  return v.u;
}
// pack two floats to packed bf16 (round-half-up): low16 = a, high16 = b
static __device__ __forceinline__ unsigned pack2(float a, float b) {
  return __builtin_amdgcn_perm(fbits(b) + 0x8000u, fbits(a) + 0x8000u, 0x07060302u);
}
static __device__ __forceinline__ f32x4 mfma16(bf16x8 a, bf16x8 b, f32x4 c) {
  return __builtin_amdgcn_mfma_f32_16x16x32_bf16(a, b, c, 0, 0, 0);
}

// ---------------- kernel 1: QKV projection (W-prep folded in; 2-dispatch pipeline) ----------------
// 512 blocks x 4 waves (64 tokens/block, 16/wave). NEW vs R5: the standalone
// prep_w dispatch is deleted. Each block converts the fp32 W (294 KB,
// L2-resident after first touch) chunk-by-chunk directly into the swizzled
// LDS image the MFMA loop consumes — byte-identical to the old dma16'd wt:
//   LDS[dd*128 + ((cin*2) ^ ((dd&7)<<4))] = bf16(W*[c6*64+cin][dd%64])
// (Q rows dd<64 pre-scaled by 0.125*log2(e)). Thread (wave,lo,quad) owns rows
// dd = wave*48 + r*16 + lo (r=0..2; 16-row groups never straddle the Q/K/V
// 64-row boundaries -> branch wave-uniform) and cins quad*16..+15 as 8 uint
// writes. Loads coalesce (16 lanes read consecutive d); ds_write banks spread
// by the XOR (~2-way, free). Double-buffered per chunk exactly as before.
__global__ __launch_bounds__(256, 2) void proj_kernel(
    const float* __restrict__ x, const float* __restrict__ wq,
    const float* __restrict__ wk, const float* __restrict__ wv,
    unsigned short* __restrict__ qo, char* __restrict__ kT,
    char* __restrict__ vT) {
  __shared__ char wls[2][24576];
  const int tid = threadIdx.x;
  const int wave = tid >> 6, lane = tid & 63;
  const int lo = lane & 15, quad = lane >> 4;
  const long tok0 = ((long)blockIdx.x * 4 + wave) * 16;

  // x fragments -> registers FIRST (long-latency HBM; the only big read)
  bf16x8 ax[12];
  const float* xr = x + (tok0 + lo) * 384 + quad * 8;
#pragma unroll
  for (int kk = 0; kk < 12; ++kk) {
    float4 x0 = *(const float4*)(xr + kk * 32);
    float4 x1 = *(const float4*)(xr + kk * 32 + 4);
    bf16x8 a;
    a[0] = (short)f2bf(x0.x); a[1] = (short)f2bf(x0.y);
    a[2] = (short)f2bf(x0.z); a[3] = (short)f2bf(x0.w);
    a[4] = (short)f2bf(x1.x); a[5] = (short)f2bf(x1.y);
    a[6] = (short)f2bf(x1.z); a[7] = (short)f2bf(x1.w);
    ax[kk] = a;
  }

  // W chunk conversion: fp32 W -> swizzled bf16 LDS image (see header comment)
  auto convert_chunk = [&](int c6, char* buf) {
#pragma unroll
    for (int r = 0; r < 3; ++r) {
      const int dd = wave * 48 + r * 16 + lo;
      const float* wsrc = (dd < 64) ? wq : (dd < 128 ? wk : wv);
      const float scale = (dd < 64) ? 0.18033688011112042f : 1.0f;
      const int drow = dd & 63;
      const int s = (dd & 7) << 4;
      char* rowp = buf + dd * 128;
#pragma unroll
      for (int j = 0; j < 8; ++j) {
        const int cin = quad * 16 + 2 * j;
        const float* cp = wsrc + (c6 * 64 + cin) * 64 + drow;
        float va = cp[0] * scale;
        float vb = cp[64] * scale;
        *(u32*)(rowp + ((quad * 32 + 4 * j) ^ s)) = pack2(va, vb);
      }
    }
  };

  convert_chunk(0, wls[0]);

  f32x4 acc[12];
#pragma unroll
  for (int nt = 0; nt < 12; ++nt) acc[nt] = (f32x4){0.f, 0.f, 0.f, 0.f};

  for (int c6 = 0; c6 < 6; ++c6) {
    const int buf = c6 & 1;
    __syncthreads();                       // chunk c6 resident; buf^1 free
    if (c6 < 5) convert_chunk(c6 + 1, wls[buf ^ 1]);
#pragma unroll
    for (int kk = 0; kk < 2; ++kk) {
      const bf16x8 axk = ax[c6 * 2 + kk];
#pragma unroll
      for (int nt = 0; nt < 12; ++nt) {
        const int dd = nt * 16 + lo;
        const int col = ((kk * 4 + quad) ^ (lo & 7)) << 4;
        bf16x8 wf = *(const bf16x8*)(&wls[buf][dd * 128 + col]);
        if (nt < 8)
          acc[nt] = mfma16(wf, axk, acc[nt]);   // Q,K: C[d][token]
        else
          acc[nt] = mfma16(axk, wf, acc[nt]);   // V:   C[token][d]
      }
    }
  }

  // epilogue: one 8-byte store per nt
  const long bb = tok0 >> 11;
  const int tin0 = (int)(tok0 & 2047);
  const int kt = tin0 >> 6;
  const long tile = ((bb * 32 + kt) << 13);   // 8192 B per tile
  const int key0w = (tin0 & 63) + quad * 4;   // V: token_local of acc rows r=0..3
  const int keyl = (tin0 & 63) + lo;          // Q/K: this lane's token
#pragma unroll
  for (int nt = 0; nt < 12; ++nt) {
    uint2 uu;
    uu.x = pack2(acc[nt][0], acc[nt][1]);
    uu.y = pack2(acc[nt][2], acc[nt][3]);
    if (nt < 4) {
      *(uint2*)(qo + (tok0 + lo) * 64 + nt * 16 + quad * 4) = uu;
    } else if (nt < 8) {
      const int d0 = (nt - 4) * 16 + quad * 4;
      *(uint2*)(kT + tile + keyl * 128 + (((d0 * 2) ^ ((keyl & 7) << 4)))) = uu;
    } else {
      const int d = (nt - 8) * 16 + lo;
      *(uint2*)(vT + tile + d * 128 + (((key0w * 2) ^ ((d & 7) << 4)))) = uu;
    }
  }
}

// ---------------- kernel 2: causal flash attention (R5-exact) ----------------
static __device__ __forceinline__ void load_tile(const char* kg, const char* vg,
                                                 int lo, int quad, int swz,
                                                 bf16x8 (&kf)[8], bf16x8 (&vf)[8]) {
#pragma unroll
  for (int t = 0; t < 4; ++t) {
    const int row = (t * 16 + lo) * 128;
    kf[2 * t] = *(const bf16x8*)(kg + row + ((quad ^ swz) << 4));
    kf[2 * t + 1] = *(const bf16x8*)(kg + row + (((4 + quad) ^ swz) << 4));
  }
#pragma unroll
  for (int kk2 = 0; kk2 < 2; ++kk2) {
#pragma unroll
    for (int dt = 0; dt < 4; ++dt) {
      const int rowv = (dt * 16 + lo) * 128;
      vf[kk2 * 4 + dt] = *(const bf16x8*)(vg + rowv + (((kk2 * 4 + quad) ^ swz) << 4));
    }
  }
}

static __device__ __forceinline__ void compute_tile(
    const bf16x8 (&kf)[8], const bf16x8 (&vf)[8], bf16x8 bq0, bf16x8 bq1,
    unsigned short* psw /* wave-private, row stride 72 */, int lo, int quad,
    bool diag, int key0, int qrl, f32x4 (&oacc)[4], float& l) {
#pragma unroll
  for (int t = 0; t < 4; ++t) {
    f32x4 s = (f32x4){0.f, 0.f, 0.f, 0.f};
    s = mfma16(kf[2 * t], bq0, s);
    s = mfma16(kf[2 * t + 1], bq1, s);
    if (diag) {
#pragma unroll
      for (int r = 0; r < 4; ++r)
        if (key0 + t * 16 + quad * 4 + r > qrl) s[r] = NEG_INF;
    }
    float e0 = __builtin_amdgcn_exp2f(s[0]);
    float e1 = __builtin_amdgcn_exp2f(s[1]);
    float e2 = __builtin_amdgcn_exp2f(s[2]);
    float e3 = __builtin_amdgcn_exp2f(s[3]);
    l += (e0 + e1) + (e2 + e3);
    uint2 uu;
    uu.x = pack2(e0, e1);
    uu.y = pack2(e2, e3);
    *(uint2*)(psw + lo * 72 + t * 16 + quad * 4) = uu;
  }
  asm volatile("s_waitcnt lgkmcnt(0)" ::: "memory");  // wave-private ps
#pragma unroll
  for (int kk2 = 0; kk2 < 2; ++kk2) {
    bf16x8 bp = *(const bf16x8*)(psw + lo * 72 + kk2 * 32 + quad * 8);
#pragma unroll
    for (int dt = 0; dt < 4; ++dt) {
      oacc[dt] = mfma16(vf[kk2 * 4 + dt], bp, oacc[dt]);
    }
  }
}

__global__ __launch_bounds__(256, 2) void attn_kernel(
    const unsigned short* __restrict__ qg, const char* __restrict__ kT,
    const char* __restrict__ vT, float* __restrict__ out) {
  __shared__ unsigned short ps[4][16][72];

  const int tid = threadIdx.x;
  const int h = tid >> 6, lane = tid & 63;
  const int lo = lane & 15, quad = lane >> 4;
  const int b = blockIdx.x & 15;
  const int idx = blockIdx.x >> 4;
  const int a = (blockIdx.x < 256) ? (31 - idx) : (idx - 16);
  const int j = 4 * a + h;
  const int niter = a + 1;
  const int qrow0 = j * 16;

  const unsigned short* qb = qg + (long)b * 2048 * 64;
  const char* kbT = kT + ((long)b * 32 << 13);
  const char* vbT = vT + ((long)b * 32 << 13);
  float* ob = out + (long)b * 2048 * 64;

  const unsigned short* qr = qb + (long)(qrow0 + lo) * 64 + quad * 8;
  const bf16x8 bq0 = *(const bf16x8*)qr;
  const bf16x8 bq1 = *(const bf16x8*)(qr + 32);

  f32x4 oacc[4];
#pragma unroll
  for (int dt = 0; dt < 4; ++dt) oacc[dt] = (f32x4){0.f, 0.f, 0.f, 0.f};
  float l = 0.f;
  const int swz = (lo & 7);
  const int qrl = qrow0 + lo;
  unsigned short* psw = &ps[h][0][0];

  bf16x8 kA[8], vA[8], kB[8], vB[8];
  load_tile(kbT, vbT, lo, quad, swz, kA, vA);

  int kt = 0;
  for (; kt + 2 <= niter; kt += 2) {
    load_tile(kbT + ((long)(kt + 1) << 13), vbT + ((long)(kt + 1) << 13), lo,
              quad, swz, kB, vB);
    compute_tile(kA, vA, bq0, bq1, psw, lo, quad, /*diag=*/false, kt * 64, qrl,
                 oacc, l);
    if (kt + 2 < niter)
      load_tile(kbT + ((long)(kt + 2) << 13), vbT + ((long)(kt + 2) << 13), lo,
                quad, swz, kA, vA);
    compute_tile(kB, vB, bq0, bq1, psw, lo, quad,
                 /*diag=*/(kt + 1 == niter - 1), (kt + 1) * 64, qrl, oacc, l);
  }
  if (kt < niter) {  // odd niter: last tile sits in A
    compute_tile(kA, vA, bq0, bq1, psw, lo, quad, /*diag=*/true, kt * 64, qrl,
                 oacc, l);
  }

  l += __shfl_xor(l, 16, 64);
  l += __shfl_xor(l, 32, 64);
  const float inv = 1.0f / l;
  float* orow = ob + (long)(qrow0 + lo) * 64;
#pragma unroll
  for (int dt = 0; dt < 4; ++dt) {
    float4 st;
    st.x = oacc[dt][0] * inv; st.y = oacc[dt][1] * inv;
    st.z = oacc[dt][2] * inv; st.w = oacc[dt][3] * inv;
    *(float4*)(orow + dt * 16 + quad * 4) = st;
  }
}

// ---------------- launcher: 2 dispatches ----------------
extern "C" void kernel_launch(void* const* d_in, const int* in_sizes, int n_in,
                              void* d_out, int out_size, void* d_ws, size_t ws_size,
                              hipStream_t stream) {
  const float* x = (const float*)d_in[0];
  const float* wq = (const float*)d_in[1];
  const float* wk = (const float*)d_in[2];
  const float* wv = (const float*)d_in[3];
  float* out = (float*)d_out;

  char* ws = (char*)d_ws;
  const size_t MB4 = (size_t)4 * 1024 * 1024;      // 16*2048*64*2 bytes
  unsigned short* qws = (unsigned short*)(ws + 147456);
  char* kT = ws + 147456 + MB4;
  char* vT = ws + 147456 + 2 * MB4;

  proj_kernel<<<512, 256, 0, stream>>>(x, wq, wk, wv, qws, kT, vT);
  attn_kernel<<<512, 256, 0, stream>>>(qws, kT, vT, out);
}

// Round 8
// 125.002 us; speedup vs baseline: 1.6987x; 1.1107x over previous
//
#include <hip/hip_runtime.h>

typedef short bf16x8 __attribute__((ext_vector_type(8)));
typedef float f32x4 __attribute__((ext_vector_type(4)));
typedef unsigned int u32;
typedef __attribute__((address_space(1))) const u32 gu32;
typedef __attribute__((address_space(3))) u32 lu32;

#define NEG_INF (-__builtin_inff())

static __device__ __forceinline__ unsigned short f2bf(float f) {
  union { float f; unsigned u; } v; v.f = f;
  return (unsigned short)((v.u + 0x7fffu + ((v.u >> 16) & 1u)) >> 16);
}
static __device__ __forceinline__ unsigned fbits(float f) {
  union { float f; unsigned u; } v; v.f = f;
  return v.u;
}
// pack two floats to packed bf16 (round-half-up): low16 = a, high16 = b
static __device__ __forceinline__ unsigned pack2(float a, float b) {
  return __builtin_amdgcn_perm(fbits(b) + 0x8000u, fbits(a) + 0x8000u, 0x07060302u);
}
static __device__ __forceinline__ f32x4 mfma16(bf16x8 a, bf16x8 b, f32x4 c) {
  return __builtin_amdgcn_mfma_f32_16x16x32_bf16(a, b, c, 0, 0, 0);
}
// async DMA: 64 lanes x 16B -> contiguous 1KB LDS at (uniform) l + lane*16
static __device__ __forceinline__ void dma16(const void* g, void* l) {
  __builtin_amdgcn_global_load_lds((gu32*)g, (lu32*)l, 16, 0, 0);
}

// ---------------- kernel 0: W -> swizzled-tiled W^T chunks ----------------
// layout: [chunk c6=c>>6][row dd (0..191: Q,K,V x 64)][64 c], byte =
// (c6*192+dd)*128 + ((cin*2) ^ ((dd&7)<<4)).  Q rows pre-scaled by 0.125*log2(e).
// NOTE (R7 lesson): keep this as a separate tiny dispatch. Folding the fp32->
// bf16 swizzle conversion into proj (512x redundant, scalar loads + ds_writes)
// cost +13 us; dma16 staging of the preconverted image is ~10x cheaper.
__global__ __launch_bounds__(256) void prep_w(const float* __restrict__ wq,
                                              const float* __restrict__ wk,
                                              const float* __restrict__ wv,
                                              char* __restrict__ wt) {
  int i = blockIdx.x * 256 + threadIdx.x;
  if (i >= 384 * 64) return;
  int c = i >> 6, d = i & 63;
  int c6 = c >> 6, cin = c & 63;
  const float Cs = 0.18033688011112042f;
  long base = (long)(c6 * 192) * 128;
  int col = (cin * 2) ^ ((d & 7) << 4);
  *(unsigned short*)(wt + base + (long)d * 128 + col) = f2bf(wq[i] * Cs);
  *(unsigned short*)(wt + base + (long)(64 + d) * 128 + col) = f2bf(wk[i]);
  *(unsigned short*)(wt + base + (long)(128 + d) * 128 + col) = f2bf(wv[i]);
}

// ---------------- kernel 1: QKV projection ----------------
// 512 blocks x 4 waves (64 tokens/block, 16/wave). W staged to LDS by 24KB
// chunks via global_load_lds (double-buffered); x held in registers.
// Q,K use mfma16(wf, axk): C[m=d][n=token]; V uses mfma16(axk, wf): C[m=token][n=d].
// Outputs: Q plain [tok][64]; K tiled-swizzled [b][kt][key][64d];
// V^T tiled-swizzled [b][kt][d][64key].
__global__ __launch_bounds__(256, 2) void proj_kernel(
    const float* __restrict__ x, const char* __restrict__ wt,
    unsigned short* __restrict__ qo, char* __restrict__ kT,
    char* __restrict__ vT) {
  __shared__ char wls[2][24576];
  const int tid = threadIdx.x;
  const int wave = tid >> 6, lane = tid & 63;
  const int lo = lane & 15, quad = lane >> 4;
  const long tok0 = ((long)blockIdx.x * 4 + wave) * 16;

  // prologue: DMA chunk 0 (24 segs of 1KB; wave issues segs wave*6..wave*6+5)
#pragma unroll
  for (int s2 = 0; s2 < 6; ++s2) {
    const int s = wave * 6 + s2;
    dma16(wt + s * 1024 + lane * 16, &wls[0][s * 1024]);
  }
  // x fragments -> registers (the only HBM read)
  bf16x8 ax[12];
  const float* xr = x + (tok0 + lo) * 384 + quad * 8;
#pragma unroll
  for (int kk = 0; kk < 12; ++kk) {
    float4 x0 = *(const float4*)(xr + kk * 32);
    float4 x1 = *(const float4*)(xr + kk * 32 + 4);
    bf16x8 a;
    a[0] = (short)f2bf(x0.x); a[1] = (short)f2bf(x0.y);
    a[2] = (short)f2bf(x0.z); a[3] = (short)f2bf(x0.w);
    a[4] = (short)f2bf(x1.x); a[5] = (short)f2bf(x1.y);
    a[6] = (short)f2bf(x1.z); a[7] = (short)f2bf(x1.w);
    ax[kk] = a;
  }

  f32x4 acc[12];
#pragma unroll
  for (int nt = 0; nt < 12; ++nt) acc[nt] = (f32x4){0.f, 0.f, 0.f, 0.f};

  for (int c6 = 0; c6 < 6; ++c6) {
    const int buf = c6 & 1;
    __syncthreads();                       // chunk c6 resident; buf^1 free
    if (c6 < 5) {
      const char* wg = wt + (long)(c6 + 1) * 24576;
#pragma unroll
      for (int s2 = 0; s2 < 6; ++s2) {
        const int s = wave * 6 + s2;
        dma16(wg + s * 1024 + lane * 16, &wls[buf ^ 1][s * 1024]);
      }
    }
#pragma unroll
    for (int kk = 0; kk < 2; ++kk) {
      const bf16x8 axk = ax[c6 * 2 + kk];
#pragma unroll
      for (int nt = 0; nt < 12; ++nt) {
        const int dd = nt * 16 + lo;
        const int col = ((kk * 4 + quad) ^ (lo & 7)) << 4;
        bf16x8 wf = *(const bf16x8*)(&wls[buf][dd * 128 + col]);
        if (nt < 8)
          acc[nt] = mfma16(wf, axk, acc[nt]);   // C[d][token]
        else
          acc[nt] = mfma16(axk, wf, acc[nt]);   // C[token][d]
      }
    }
  }

  // epilogue: one 8-byte store per nt
  const long bb = tok0 >> 11;
  const int tin0 = (int)(tok0 & 2047);
  const int kt = tin0 >> 6;
  const long tile = ((bb * 32 + kt) << 13);   // 8192 B per tile
  const int key0w = (tin0 & 63) + quad * 4;   // V: token_local of acc rows r=0..3
  const int keyl = (tin0 & 63) + lo;          // Q/K: this lane's token
#pragma unroll
  for (int nt = 0; nt < 12; ++nt) {
    uint2 uu;
    uu.x = pack2(acc[nt][0], acc[nt][1]);
    uu.y = pack2(acc[nt][2], acc[nt][3]);
    if (nt < 4) {
      *(uint2*)(qo + (tok0 + lo) * 64 + nt * 16 + quad * 4) = uu;
    } else if (nt < 8) {
      const int d0 = (nt - 4) * 16 + quad * 4;
      *(uint2*)(kT + tile + keyl * 128 + (((d0 * 2) ^ ((keyl & 7) << 4)))) = uu;
    } else {
      const int d = (nt - 8) * 16 + lo;
      *(uint2*)(vT + tile + d * 128 + (((key0w * 2) ^ ((d & 7) << 4)))) = uu;
    }
  }
}

// ---------------- kernel 2: causal flash attention, reg-double-buffered ----------------
// 512 blocks x 4 waves; K/V read directly from the tiled-swizzled global layout
// (L1/L2-resident; no LDS staging, no __syncthreads). Software pipeline across
// key-tiles with named register sets A/B — tile kt+1's 16 loads issue BEFORE
// tile kt's compute, hiding L2 latency under MFMA/softmax.
static __device__ __forceinline__ void load_tile(const char* kg, const char* vg,
                                                 int lo, int quad, int swz,
                                                 bf16x8 (&kf)[8], bf16x8 (&vf)[8]) {
#pragma unroll
  for (int t = 0; t < 4; ++t) {
    const int row = (t * 16 + lo) * 128;
    kf[2 * t] = *(const bf16x8*)(kg + row + ((quad ^ swz) << 4));
    kf[2 * t + 1] = *(const bf16x8*)(kg + row + (((4 + quad) ^ swz) << 4));
  }
#pragma unroll
  for (int kk2 = 0; kk2 < 2; ++kk2) {
#pragma unroll
    for (int dt = 0; dt < 4; ++dt) {
      const int rowv = (dt * 16 + lo) * 128;
      vf[kk2 * 4 + dt] = *(const bf16x8*)(vg + rowv + (((kk2 * 4 + quad) ^ swz) << 4));
    }
  }
}

static __device__ __forceinline__ void compute_tile(
    const bf16x8 (&kf)[8], const bf16x8 (&vf)[8], bf16x8 bq0, bf16x8 bq1,
    unsigned short* psw /* wave-private, row stride 72 */, int lo, int quad,
    bool diag, int key0, int qrl, f32x4 (&oacc)[4], float& l) {
#pragma unroll
  for (int t = 0; t < 4; ++t) {
    f32x4 s = (f32x4){0.f, 0.f, 0.f, 0.f};
    s = mfma16(kf[2 * t], bq0, s);
    s = mfma16(kf[2 * t + 1], bq1, s);
    if (diag) {
#pragma unroll
      for (int r = 0; r < 4; ++r)
        if (key0 + t * 16 + quad * 4 + r > qrl) s[r] = NEG_INF;
    }
    float e0 = __builtin_amdgcn_exp2f(s[0]);
    float e1 = __builtin_amdgcn_exp2f(s[1]);
    float e2 = __builtin_amdgcn_exp2f(s[2]);
    float e3 = __builtin_amdgcn_exp2f(s[3]);
    l += (e0 + e1) + (e2 + e3);
    uint2 uu;
    uu.x = pack2(e0, e1);
    uu.y = pack2(e2, e3);
    *(uint2*)(psw + lo * 72 + t * 16 + quad * 4) = uu;
  }
  asm volatile("s_waitcnt lgkmcnt(0)" ::: "memory");  // wave-private ps
#pragma unroll
  for (int kk2 = 0; kk2 < 2; ++kk2) {
    bf16x8 bp = *(const bf16x8*)(psw + lo * 72 + kk2 * 32 + quad * 8);
#pragma unroll
    for (int dt = 0; dt < 4; ++dt) {
      oacc[dt] = mfma16(vf[kk2 * 4 + dt], bp, oacc[dt]);
    }
  }
}

__global__ __launch_bounds__(256, 2) void attn_kernel(
    const unsigned short* __restrict__ qg, const char* __restrict__ kT,
    const char* __restrict__ vT, float* __restrict__ out) {
  __shared__ unsigned short ps[4][16][72];  // wave-private P^T [qrow][key]

  const int tid = threadIdx.x;
  const int h = tid >> 6, lane = tid & 63;
  const int lo = lane & 15, quad = lane >> 4;
  const int b = blockIdx.x & 15;
  const int idx = blockIdx.x >> 4;
  const int a = (blockIdx.x < 256) ? (31 - idx) : (idx - 16);
  const int j = 4 * a + h;
  const int niter = a + 1;
  const int qrow0 = j * 16;

  const unsigned short* qb = qg + (long)b * 2048 * 64;
  const char* kbT = kT + ((long)b * 32 << 13);
  const char* vbT = vT + ((long)b * 32 << 13);
  float* ob = out + (long)b * 2048 * 64;

  // Q fragments (B-operand), pre-scaled by 0.125*log2(e)
  const unsigned short* qr = qb + (long)(qrow0 + lo) * 64 + quad * 8;
  const bf16x8 bq0 = *(const bf16x8*)qr;
  const bf16x8 bq1 = *(const bf16x8*)(qr + 32);

  f32x4 oacc[4];
#pragma unroll
  for (int dt = 0; dt < 4; ++dt) oacc[dt] = (f32x4){0.f, 0.f, 0.f, 0.f};
  float l = 0.f;
  const int swz = (lo & 7);
  const int qrl = qrow0 + lo;
  unsigned short* psw = &ps[h][0][0];

  bf16x8 kA[8], vA[8], kB[8], vB[8];
  load_tile(kbT, vbT, lo, quad, swz, kA, vA);

  int kt = 0;
  for (; kt + 2 <= niter; kt += 2) {
    // prefetch tile kt+1 into B before computing tile kt from A
    load_tile(kbT + ((long)(kt + 1) << 13), vbT + ((long)(kt + 1) << 13), lo,
              quad, swz, kB, vB);
    compute_tile(kA, vA, bq0, bq1, psw, lo, quad, /*diag=*/false, kt * 64, qrl,
                 oacc, l);
    if (kt + 2 < niter)
      load_tile(kbT + ((long)(kt + 2) << 13), vbT + ((long)(kt + 2) << 13), lo,
                quad, swz, kA, vA);
    compute_tile(kB, vB, bq0, bq1, psw, lo, quad,
                 /*diag=*/(kt + 1 == niter - 1), (kt + 1) * 64, qrl, oacc, l);
  }
  if (kt < niter) {  // odd niter: last tile sits in A
    compute_tile(kA, vA, bq0, bq1, psw, lo, quad, /*diag=*/true, kt * 64, qrl,
                 oacc, l);
  }

  // epilogue: per-wave complete rows — reduce l over quads, normalize, store
  l += __shfl_xor(l, 16, 64);
  l += __shfl_xor(l, 32, 64);
  const float inv = 1.0f / l;
  float* orow = ob + (long)(qrow0 + lo) * 64;
#pragma unroll
  for (int dt = 0; dt < 4; ++dt) {
    float4 st;
    st.x = oacc[dt][0] * inv; st.y = oacc[dt][1] * inv;
    st.z = oacc[dt][2] * inv; st.w = oacc[dt][3] * inv;
    *(float4*)(orow + dt * 16 + quad * 4) = st;
  }
}

// ---------------- launcher ----------------
extern "C" void kernel_launch(void* const* d_in, const int* in_sizes, int n_in,
                              void* d_out, int out_size, void* d_ws, size_t ws_size,
                              hipStream_t stream) {
  const float* x = (const float*)d_in[0];
  const float* wq = (const float*)d_in[1];
  const float* wk = (const float*)d_in[2];
  const float* wv = (const float*)d_in[3];
  float* out = (float*)d_out;

  char* ws = (char*)d_ws;
  char* wt = ws;                                   // 147456 B (6 chunks x 24576)
  const size_t MB4 = (size_t)4 * 1024 * 1024;      // 16*2048*64*2 bytes
  unsigned short* qws = (unsigned short*)(ws + 147456);
  char* kT = ws + 147456 + MB4;
  char* vT = ws + 147456 + 2 * MB4;

  prep_w<<<96, 256, 0, stream>>>(wq, wk, wv, wt);
  proj_kernel<<<512, 256, 0, stream>>>(x, wt, qws, kT, vT);
  attn_kernel<<<512, 256, 0, stream>>>(qws, kT, vT, out);
}